// Round 3
// baseline (109.877 us; speedup 1.0000x reference)
//
#include <hip/hip_runtime.h>

typedef short bf16x8 __attribute__((ext_vector_type(8)));
typedef float f32x4  __attribute__((ext_vector_type(4)));

#define L_RES 1280
#define A_ATM 14
#define K_NB  30
#define EPB   15           // edges per block (30 split across 2 blocks per residue)
#define FEAT  656
#define KPAD  672          // 656 padded to 21*32 for the MFMA K-loop
#define NCH   128
#define AF_STRIDE 680      // start-bank class (5f+q)&7 covers all 8 -> conflict-free b128
#define E_OUT_OFF (L_RES * K_NB * NCH)

// fp32 -> bf16 round-to-nearest-even
__device__ __forceinline__ ushort f2bf(float x) {
    union { float f; unsigned u; } v; v.f = x;
    unsigned r = (v.u + 0x7fffu + ((v.u >> 16) & 1u)) >> 16;
    return (ushort)r;
}

// W_edge [656][128] fp32  ->  Wt [128][672] bf16 (k-padded with zeros)
__global__ __launch_bounds__(256) void wt_convert_kernel(const float* __restrict__ W,
                                                         ushort* __restrict__ Wt) {
    int idx = blockIdx.x * 256 + threadIdx.x;   // n*KPAD + k
    if (idx >= NCH * KPAD) return;
    int n = idx / KPAD, k = idx - n * KPAD;
    float v = (k < FEAT) ? W[k * NCH + n] : 0.0f;
    Wt[idx] = f2bf(v);
}

__global__ __launch_bounds__(256, 7) void sidechain_feat_kernel(
    const float* __restrict__ X,
    const int*   __restrict__ ridx,
    const int*   __restrict__ clab,
    const int*   __restrict__ Eidx,
    const float* __restrict__ Wpos,
    const float* __restrict__ bpos,
    const ushort* __restrict__ Wt,     // bf16 [128][672]
    const float* __restrict__ gamma,
    const float* __restrict__ beta,
    float* __restrict__ out)
{
    __shared__ __align__(16) ushort Af[16][AF_STRIDE];   // 21,760 B
    __shared__ __align__(16) float part[16][4][2];       // per-row (sum, sumsq) per wave

    const int blk  = blockIdx.x;
    const int i    = blk >> 1;         // residue
    const int h    = blk & 1;          // which half of the 30 edges
    const int ebase = h * EPB;
    const int t    = threadIdx.x;
    const int w    = t >> 6;           // wave 0..3
    const int lane = t & 63;
    const int frow = lane & 15;
    const int quad = lane >> 4;
    const int c0 = w * 32 + frow;      // wave's two output columns
    const int c1 = c0 + 16;

    // ---- early independent global prefetch: B chunks 0,1 + gamma/beta ----
    const ushort* B0p = Wt + (size_t)c0 * KPAD + quad * 8;
    const ushort* B1p = Wt + (size_t)c1 * KPAD + quad * 8;
    bf16x8 b0c = *(const bf16x8*)(B0p);
    bf16x8 b1c = *(const bf16x8*)(B1p);
    bf16x8 b0n = *(const bf16x8*)(B0p + 32);
    bf16x8 b1n = *(const bf16x8*)(B1p + 32);
    float gg0 = gamma[c0], gg1 = gamma[c1];
    float be0 = beta[c0],  be1 = beta[c1];

    // ---- E_idx passthrough (independent, before any barrier) ----
    if (t < EPB)
        out[E_OUT_OFF + i * K_NB + ebase + t] = (float)Eidx[i * K_NB + ebase + t];

    const int my_clab = clab[i];       // block-uniform (L1 broadcast)
    const int my_ridx = ridx[i];

    // ---- positional features (cols 0..15): EPB*16 = 240 items, one pass ----
    if (t < EPB * 16) {
        int e = t >> 4, c = t & 15;
        int j = Eidx[i * K_NB + ebase + e];
        int d;
        if (my_clab == clab[j]) {
            int off = my_ridx - ridx[j] + 32;
            d = off < 0 ? 0 : (off > 64 ? 64 : off);
        } else {
            d = 65;
        }
        Af[e][c] = f2bf(Wpos[d * 16 + c] + bpos[c]);
    }
    // ---- zero k-pad cols 656..671 of valid rows (pad NaN x B-pad 0 would poison C) ----
    if (t < EPB * 16) Af[t >> 4][FEAT + (t & 15)] = 0;
    // row 15 stays garbage: it only feeds discarded C row 15 (MFMA rows independent)

    // ---- RBF features: EPB*40 = 600 items, direct X gathers, no nbr/bbs LDS ----
#pragma unroll
    for (int u = 0; u < 3; ++u) {
        int idx = t + u * 256;
        if (idx < EPB * 40) {
            int e  = idx / 40;
            int p  = idx - e * 40;
            int ab = p / 10, as = p - ab * 10;
            const int perm[4] = {1, 0, 2, 3};
            int j = Eidx[i * K_NB + ebase + e];
            const float* xb = X + (size_t)(i * A_ATM + perm[ab]) * 3;   // L1 broadcast
            const float* xp = X + (size_t)(j * A_ATM + 4 + as) * 3;
            float dx = xb[0] - xp[0];
            float dy = xb[1] - xp[1];
            float dz = xb[2] - xp[2];
            float dist = sqrtf(dx * dx + dy * dy + dz * dz + 1e-6f);
            bool self = (j == i);      // AUTOREGRESSIVE: zero RBF on self edges
            unsigned* dst = (unsigned*)&Af[e][16 + p * 16];
#pragma unroll
            for (int q = 0; q < 8; ++q) {
                float m0 = 2.0f + (float)(2 * q)     * (20.0f / 15.0f);
                float m1 = 2.0f + (float)(2 * q + 1) * (20.0f / 15.0f);
                float a0 = (dist - m0) * 0.8f;
                float a1 = (dist - m1) * 0.8f;
                float r0 = self ? 0.0f : __expf(-a0 * a0);
                float r1 = self ? 0.0f : __expf(-a1 * a1);
                unsigned pk;
                asm("v_cvt_pk_bf16_f32 %0, %1, %2" : "=v"(pk) : "v"(r0), "v"(r1));
                dst[q] = pk;
            }
        }
    }
    __syncthreads();                   // barrier 1: Af ready

    // ---- MFMA GEMM: C[16 x 128] = Af[16 x 672] @ Wt^T (bf16 -> fp32) ----
    const ushort* A0p = &Af[frow][quad * 8];
    bf16x8 a0c = *(const bf16x8*)(A0p);

    f32x4 acc00 = {0.f,0.f,0.f,0.f}, acc01 = {0.f,0.f,0.f,0.f};

#pragma unroll
    for (int c = 0; c < 21; ++c) {
        bf16x8 ua0 = a0c, ub0 = b0c, ub1 = b1c;
        if (c + 1 < 21)                                   // depth-1 A prefetch (LDS)
            a0c = *(const bf16x8*)(A0p + (c + 1) * 32);
        b0c = b0n; b1c = b1n;
        if (c + 2 < 21) {                                 // depth-2 B prefetch (global)
            b0n = *(const bf16x8*)(B0p + (c + 2) * 32);
            b1n = *(const bf16x8*)(B1p + (c + 2) * 32);
        }
        acc00 = __builtin_amdgcn_mfma_f32_16x16x32_bf16(ua0, ub0, acc00, 0, 0, 0);
        acc01 = __builtin_amdgcn_mfma_f32_16x16x32_bf16(ua0, ub1, acc01, 0, 0, 0);
    }

    // ---- register LayerNorm: per-wave 32-col partials via 16-lane butterfly ----
    // C/D layout (verified m89/m91): col = lane&15, row = quad*4 + reg
    float s0[4], q0[4];
#pragma unroll
    for (int r = 0; r < 4; ++r) {
        s0[r] = acc00[r] + acc01[r];
        q0[r] = acc00[r] * acc00[r] + acc01[r] * acc01[r];
    }
#pragma unroll
    for (int off = 1; off < 16; off <<= 1) {
#pragma unroll
        for (int r = 0; r < 4; ++r) {
            s0[r] += __shfl_xor(s0[r], off);
            q0[r] += __shfl_xor(q0[r], off);
        }
    }
    if (frow == 0) {
#pragma unroll
        for (int r = 0; r < 4; ++r) {
            int row = quad * 4 + r;
            part[row][w][0] = s0[r];
            part[row][w][1] = q0[r];
        }
    }
    __syncthreads();                   // barrier 2: partials ready

    // ---- finalize LN + store straight from accumulators ----
#pragma unroll
    for (int r = 0; r < 4; ++r) {
        int row = quad * 4 + r;        // 0..15; row 15 discarded (EPB=15)
        if (row < EPB) {
            f32x4 pa = *(const f32x4*)&part[row][0][0];
            f32x4 pb = *(const f32x4*)&part[row][2][0];
            float S = pa[0] + pa[2] + pb[0] + pb[2];
            float Q = pa[1] + pa[3] + pb[1] + pb[3];
            float mean = S * (1.0f / 128.0f);
            float rstd = rsqrtf(Q * (1.0f / 128.0f) - mean * mean + 1e-5f);
            float* o = out + (size_t)(i * K_NB + ebase + row) * NCH;
            o[c0] = (acc00[r] - mean) * rstd * gg0 + be0;
            o[c1] = (acc01[r] - mean) * rstd * gg1 + be1;
        }
    }
}

extern "C" void kernel_launch(void* const* d_in, const int* in_sizes, int n_in,
                              void* d_out, int out_size, void* d_ws, size_t ws_size,
                              hipStream_t stream) {
    const float* X     = (const float*)d_in[0];
    const int*   ridx  = (const int*)  d_in[1];
    const int*   clab  = (const int*)  d_in[2];
    const int*   Eidx  = (const int*)  d_in[3];
    // d_in[4] = atom_mask (unused by reference forward)
    const float* Wpos  = (const float*)d_in[5];
    const float* bpos  = (const float*)d_in[6];
    const float* Wedge = (const float*)d_in[7];
    const float* gamma = (const float*)d_in[8];
    const float* beta  = (const float*)d_in[9];
    float* out = (float*)d_out;

    // ws poison fill is unconditional (round-1 evidence) -> using ws is free.
    ushort* Wt = (ushort*)d_ws;   // 128*672*2 = 172,032 B

    wt_convert_kernel<<<(NCH * KPAD + 255) / 256, 256, 0, stream>>>(Wedge, Wt);
    sidechain_feat_kernel<<<2 * L_RES, 256, 0, stream>>>(
        X, ridx, clab, Eidx, Wpos, bpos, Wt, gamma, beta, out);
}

// Round 4
// 105.074 us; speedup vs baseline: 1.0457x; 1.0457x over previous
//
#include <hip/hip_runtime.h>

typedef short bf16x8 __attribute__((ext_vector_type(8)));
typedef float f32x4  __attribute__((ext_vector_type(4)));

#define L_RES 1280
#define A_ATM 14
#define K_NB  30
#define FEAT  656
#define KPAD  672          // 656 padded to 21*32 for the MFMA K-loop
#define NCH   128
#define WAVES 8
#define AF_STRIDE 680      // start-bank class (5f+q)&7 covers all 8 -> conflict-free b128
#define E_OUT_OFF (L_RES * K_NB * NCH)

// fp32 -> bf16 round-to-nearest-even
__device__ __forceinline__ ushort f2bf(float x) {
    union { float f; unsigned u; } v; v.f = x;
    unsigned r = (v.u + 0x7fffu + ((v.u >> 16) & 1u)) >> 16;
    return (ushort)r;
}

// W_edge [656][128] fp32  ->  Wt [128][672] bf16 (k-padded with zeros)
__global__ __launch_bounds__(256) void wt_convert_kernel(const float* __restrict__ W,
                                                         ushort* __restrict__ Wt) {
    int idx = blockIdx.x * 256 + threadIdx.x;   // n*KPAD + k
    if (idx >= NCH * KPAD) return;
    int n = idx / KPAD, k = idx - n * KPAD;
    float v = (k < FEAT) ? W[k * NCH + n] : 0.0f;
    Wt[idx] = f2bf(v);
}

__global__ __launch_bounds__(512, 6) void sidechain_feat_kernel(
    const float* __restrict__ X,
    const int*   __restrict__ ridx,
    const int*   __restrict__ clab,
    const int*   __restrict__ Eidx,
    const float* __restrict__ Wpos,
    const float* __restrict__ bpos,
    const ushort* __restrict__ Wt,     // bf16 [128][672]
    const float* __restrict__ gamma,
    const float* __restrict__ beta,
    float* __restrict__ out)
{
    __shared__ __align__(16) ushort Af[32][AF_STRIDE];     // 43,520 B
    __shared__ __align__(16) float part[32][WAVES][2];     // 2,048 B

    const int i    = blockIdx.x;       // residue
    const int t    = threadIdx.x;
    const int w    = t >> 6;           // wave 0..7
    const int lane = t & 63;
    const int frow = lane & 15;
    const int quad = lane >> 4;
    const int c0   = w * 16 + frow;    // wave's single output column set

    // ---- E_idx passthrough + positional loads first (head of dependent chain) ----
    if (t < K_NB)
        out[E_OUT_OFF + i * K_NB + t] = (float)Eidx[i * K_NB + t];

    const int my_clab = clab[i];       // block-uniform (L1 broadcast)
    const int my_ridx = ridx[i];

    // ---- positional features (cols 0..15): 480 items, one pass ----
    if (t < K_NB * 16) {
        int e = t >> 4, c = t & 15;
        int j = Eidx[i * K_NB + e];
        int d;
        if (my_clab == clab[j]) {
            int off = my_ridx - ridx[j] + 32;
            d = off < 0 ? 0 : (off > 64 ? 64 : off);
        } else {
            d = 65;
        }
        Af[e][c] = f2bf(Wpos[d * 16 + c] + bpos[c]);
    }
    // zero k-pad cols 656..671 of valid rows (garbage NaN x Wt-pad 0 would poison C)
    if (t < K_NB * 16) Af[t >> 4][FEAT + (t & 15)] = 0;
    // rows 30,31 stay garbage: they only feed discarded C rows 30,31

    // ---- B prefetch depth-3 + gamma/beta (independent of features) ----
    const ushort* B0p = Wt + (size_t)c0 * KPAD + quad * 8;
    bf16x8 b0 = *(const bf16x8*)(B0p);
    bf16x8 b1 = *(const bf16x8*)(B0p + 32);
    bf16x8 b2 = *(const bf16x8*)(B0p + 64);
    float gg = gamma[c0], be = beta[c0];

    // ---- RBF features: 1200 (edge, pair) items, direct X gathers ----
#pragma unroll
    for (int u = 0; u < 3; ++u) {
        int idx = t + u * 512;
        if (idx < K_NB * 40) {
            int e  = idx / 40;
            int p  = idx - e * 40;
            int ab = p / 10, as = p - ab * 10;
            const int perm[4] = {1, 0, 2, 3};
            int j = Eidx[i * K_NB + e];
            const float* xb = X + (size_t)(i * A_ATM + perm[ab]) * 3;   // L1 broadcast
            const float* xp = X + (size_t)(j * A_ATM + 4 + as) * 3;
            float dx = xb[0] - xp[0];
            float dy = xb[1] - xp[1];
            float dz = xb[2] - xp[2];
            float dist = sqrtf(dx * dx + dy * dy + dz * dz + 1e-6f);
            bool self = (j == i);      // AUTOREGRESSIVE: zero RBF on self edges
            unsigned* dst = (unsigned*)&Af[e][16 + p * 16];
#pragma unroll
            for (int q = 0; q < 8; ++q) {
                float m0 = 2.0f + (float)(2 * q)     * (20.0f / 15.0f);
                float m1 = 2.0f + (float)(2 * q + 1) * (20.0f / 15.0f);
                float a0 = (dist - m0) * 0.8f;
                float a1 = (dist - m1) * 0.8f;
                float r0 = self ? 0.0f : __expf(-a0 * a0);
                float r1 = self ? 0.0f : __expf(-a1 * a1);
                unsigned pk;
                asm("v_cvt_pk_bf16_f32 %0, %1, %2" : "=v"(pk) : "v"(r0), "v"(r1));
                dst[q] = pk;
            }
        }
    }
    __syncthreads();                   // barrier 1: Af ready

    // ---- MFMA GEMM: C[32 x 128] = Af[32 x 672] @ Wt^T; wave owns 16 cols ----
    const ushort* A0p = &Af[frow][quad * 8];
    const ushort* A1p = &Af[16 + frow][quad * 8];
    bf16x8 a0 = *(const bf16x8*)(A0p);
    bf16x8 a1 = *(const bf16x8*)(A1p);

    f32x4 acc0 = {0.f,0.f,0.f,0.f}, acc1 = {0.f,0.f,0.f,0.f};

#pragma unroll
    for (int c = 0; c < 21; ++c) {
        bf16x8 ua0 = a0, ua1 = a1, ub = b0;
        if (c + 1 < 21) {                                 // depth-1 A prefetch (LDS)
            a0 = *(const bf16x8*)(A0p + (c + 1) * 32);
            a1 = *(const bf16x8*)(A1p + (c + 1) * 32);
        }
        b0 = b1; b1 = b2;
        if (c + 3 < 21)                                   // depth-3 B prefetch (global/L2)
            b2 = *(const bf16x8*)(B0p + (c + 3) * 32);
        acc0 = __builtin_amdgcn_mfma_f32_16x16x32_bf16(ua0, ub, acc0, 0, 0, 0);
        acc1 = __builtin_amdgcn_mfma_f32_16x16x32_bf16(ua1, ub, acc1, 0, 0, 0);
    }

    // ---- register LayerNorm: per-wave 16-col partials via 16-lane butterfly ----
    // C/D layout (verified m89/m91): col = lane&15, row = quad*4 + reg
    float s0[4], q0[4], s1[4], q1[4];
#pragma unroll
    for (int r = 0; r < 4; ++r) {
        s0[r] = acc0[r];
        q0[r] = acc0[r] * acc0[r];
        s1[r] = acc1[r];
        q1[r] = acc1[r] * acc1[r];
    }
#pragma unroll
    for (int off = 1; off < 16; off <<= 1) {
#pragma unroll
        for (int r = 0; r < 4; ++r) {
            s0[r] += __shfl_xor(s0[r], off);
            q0[r] += __shfl_xor(q0[r], off);
            s1[r] += __shfl_xor(s1[r], off);
            q1[r] += __shfl_xor(q1[r], off);
        }
    }
    if (frow == 0) {
#pragma unroll
        for (int r = 0; r < 4; ++r) {
            int row = quad * 4 + r;
            part[row][w][0]      = s0[r];
            part[row][w][1]      = q0[r];
            part[16 + row][w][0] = s1[r];
            part[16 + row][w][1] = q1[r];
        }
    }
    __syncthreads();                   // barrier 2: partials ready

    // ---- finalize LN + store straight from accumulators ----
#pragma unroll
    for (int r = 0; r < 4; ++r) {
        int row = quad * 4 + r;        // 0..15, always valid
        {
            f32x4 pa = *(const f32x4*)&part[row][0][0];
            f32x4 pb = *(const f32x4*)&part[row][2][0];
            f32x4 pc = *(const f32x4*)&part[row][4][0];
            f32x4 pd = *(const f32x4*)&part[row][6][0];
            float S = pa[0] + pa[2] + pb[0] + pb[2] + pc[0] + pc[2] + pd[0] + pd[2];
            float Q = pa[1] + pa[3] + pb[1] + pb[3] + pc[1] + pc[3] + pd[1] + pd[3];
            float mean = S * (1.0f / 128.0f);
            float rstd = rsqrtf(Q * (1.0f / 128.0f) - mean * mean + 1e-5f);
            out[(size_t)(i * K_NB + row) * NCH + c0] = (acc0[r] - mean) * rstd * gg + be;
        }
        int row1 = 16 + row;           // 16..31; rows 30,31 discarded
        if (row1 < K_NB) {
            f32x4 pa = *(const f32x4*)&part[row1][0][0];
            f32x4 pb = *(const f32x4*)&part[row1][2][0];
            f32x4 pc = *(const f32x4*)&part[row1][4][0];
            f32x4 pd = *(const f32x4*)&part[row1][6][0];
            float S = pa[0] + pa[2] + pb[0] + pb[2] + pc[0] + pc[2] + pd[0] + pd[2];
            float Q = pa[1] + pa[3] + pb[1] + pb[3] + pc[1] + pc[3] + pd[1] + pd[3];
            float mean = S * (1.0f / 128.0f);
            float rstd = rsqrtf(Q * (1.0f / 128.0f) - mean * mean + 1e-5f);
            out[(size_t)(i * K_NB + row1) * NCH + c0] = (acc1[r] - mean) * rstd * gg + be;
        }
    }
}

extern "C" void kernel_launch(void* const* d_in, const int* in_sizes, int n_in,
                              void* d_out, int out_size, void* d_ws, size_t ws_size,
                              hipStream_t stream) {
    const float* X     = (const float*)d_in[0];
    const int*   ridx  = (const int*)  d_in[1];
    const int*   clab  = (const int*)  d_in[2];
    const int*   Eidx  = (const int*)  d_in[3];
    // d_in[4] = atom_mask (unused by reference forward)
    const float* Wpos  = (const float*)d_in[5];
    const float* bpos  = (const float*)d_in[6];
    const float* Wedge = (const float*)d_in[7];
    const float* gamma = (const float*)d_in[8];
    const float* beta  = (const float*)d_in[9];
    float* out = (float*)d_out;

    // ws poison fill is unconditional (round-1 evidence) -> using ws is free.
    ushort* Wt = (ushort*)d_ws;   // 128*672*2 = 172,032 B

    wt_convert_kernel<<<(NCH * KPAD + 255) / 256, 256, 0, stream>>>(Wedge, Wt);
    sidechain_feat_kernel<<<L_RES, 512, 0, stream>>>(
        X, ridx, clab, Eidx, Wpos, bpos, Wt, gamma, beta, out);
}